// Round 8
// baseline (256.616 us; speedup 1.0000x reference)
//
#include <hip/hip_runtime.h>
#include <hip/hip_bf16.h>
#include <stdint.h>

typedef short bf16x8 __attribute__((ext_vector_type(8)));
typedef float f32x4  __attribute__((ext_vector_type(4)));

#define B_   32
#define CIN  32
#define COUT 64
#define H_   128
#define W_   128
#define HW   (H_ * W_)
#define T_   4            // output rows per block
#define RROWS 6           // staged input rows = T_+2
#define PXW  130          // padded width
#define NT_  512          // threads per block (8 waves)
#define SCW  68           // scratch row stride in words (16B-aligned, 2-way banks)

// s_waitcnt imm: vmcnt=63, expcnt=7, lgkmcnt=0  -> wait LDS only, NOT stores
#define WAIT_LGKM0() __builtin_amdgcn_s_waitcnt(0xC07F)

static __device__ __forceinline__ ushort f2bf(float v) {
    __hip_bfloat16 h = __float2bfloat16(v);
    return __builtin_bit_cast(ushort, h);
}

// ---------------------------------------------------------------------------
// Weight pack: [Cout][Cin][3][3] fp32 -> bf16 A-fragment order
// Wp[tap][ocg][lane][j] = W[ocg*16 + (lane&15)][8*(lane>>4)+j][ky][kx]
// ---------------------------------------------------------------------------
__global__ void prep_w_kernel(const float* __restrict__ wt, ushort* __restrict__ Wp) {
    int p = blockIdx.x * blockDim.x + threadIdx.x;
    if (p >= COUT * CIN * 9) return;  // 18432
    int j    = p & 7;
    int lane = (p >> 3) & 63;
    int g    = (p >> 9) & 3;
    int tap  = p >> 11;
    int oc   = g * 16 + (lane & 15);
    int cin  = (lane >> 4) * 8 + j;
    int ky   = tap / 3;
    int kx   = tap % 3;
    Wp[p] = f2bf(wt[(((size_t)oc * CIN + cin) * 3 + ky) * 3 + kx]);
}

// ---------------------------------------------------------------------------
// Fused conv, 8-wave blocks. Block = (b, 4 output rows); stage 6 padded rows
// (NCHW fp32 -> bf16 NHWC in LDS, XOR-swizzled); wave = (row = wid>>1,
// px-half = wid&1) computes 64 oc x 64 px via 144 MFMA; full-line epilogue
// through per-wave LDS scratch overlaid on the (dead) staging buffer.
// 49.9 KB LDS -> 3 blocks/CU = 24 waves/CU.
// ---------------------------------------------------------------------------
__global__ __launch_bounds__(NT_, 6) void conv_fused_kernel(
    const float* __restrict__ in, const ushort* __restrict__ Wp,
    float* __restrict__ out) {
    __shared__ ushort lds[RROWS * PXW * 32];     // 49,920 B (staging + scratch)

    int hw_blk  = blockIdx.x;
    int logical = (hw_blk & 7) * 128 + (hw_blk >> 3);   // grid = 1024 = 8*128
    int b   = logical >> 5;          // /32
    int h0  = (logical & 31) * T_;
    int tid = threadIdx.x;

    // ---- stage: thread = one (row, px) column, loop 32 channels ----
    for (int i = tid; i < RROWS * PXW; i += NT_) {
        int r  = i / PXW;
        int px = i - r * PXW;
        int gy = h0 + r - 1;
        bf16x8 v[4];
        if (gy >= 0 && gy < H_ && px >= 1 && px <= W_) {
            const float* src = in + ((size_t)b * CIN * H_ + gy) * W_ + (px - 1);
#pragma unroll
            for (int q = 0; q < 4; ++q)
#pragma unroll
                for (int j = 0; j < 8; ++j)
                    v[q][j] = (short)f2bf(src[(size_t)(q * 8 + j) * HW]);
        } else {
#pragma unroll
            for (int q = 0; q < 4; ++q)
#pragma unroll
                for (int j = 0; j < 8; ++j)
                    v[q][j] = 0;
        }
        uint32_t base_byte = (uint32_t)i * 64;
        uint32_t sw = ((uint32_t)(px >> 1) & 3u) << 4;
#pragma unroll
        for (int q = 0; q < 4; ++q)
            *(bf16x8*)((char*)lds + base_byte + (((uint32_t)q << 4) ^ sw)) = v[q];
    }
    __syncthreads();

    // ---- compute: wave = (row = wid>>1, px half = wid&1), 64 oc x 64 px ----
    int wid  = tid >> 6;
    int lane = tid & 63;
    int llo  = lane & 15;
    int lhi  = lane >> 4;
    int row  = wid >> 1;            // 0..3
    int px0  = (wid & 1) * 64;
    int h    = h0 + row;

    f32x4 acc[4][4];
#pragma unroll
    for (int g = 0; g < 4; ++g)
#pragma unroll
        for (int nf = 0; nf < 4; ++nf) {
            acc[g][nf][0] = 0.f; acc[g][nf][1] = 0.f;
            acc[g][nf][2] = 0.f; acc[g][nf][3] = 0.f;
        }

#pragma unroll
    for (int tap = 0; tap < 9; ++tap) {
        int dy = tap / 3;
        int dx = tap % 3;
        int rbase = (row + dy) * PXW;
        bf16x8 Af[4];
#pragma unroll
        for (int g = 0; g < 4; ++g)
            Af[g] = *(const bf16x8*)(Wp + ((size_t)(tap * 4 + g) * 64 + lane) * 8);
#pragma unroll
        for (int nf = 0; nf < 4; ++nf) {
            int px = px0 + nf * 16 + llo + dx;
            uint32_t byte = (uint32_t)(rbase + px) * 64u +
                            (((uint32_t)lhi << 4) ^ ((((uint32_t)px >> 1) & 3u) << 4));
            bf16x8 Bf = *(const bf16x8*)((const char*)lds + byte);
#pragma unroll
            for (int g = 0; g < 4; ++g)
                acc[g][nf] = __builtin_amdgcn_mfma_f32_16x16x32_bf16(Af[g], Bf, acc[g][nf], 0, 0, 0);
        }
    }

    // staging buffer is dead now; re-use it as per-wave f32 scratch
    __syncthreads();

    // ---- epilogue: per-wave LDS transpose -> full-line dwordx4 stores ----
    // acc[g][nf][r] is (oc' = lhi*4+r, px' = nf*16+llo). Readback: oc'=j*4+lhi,
    // px' = llo*4..+3 -> f32x4; 16 lanes cover 256B contiguous (full lines).
    float* myscr = (float*)lds + wid * 16 * SCW;
    float* obase = out + (size_t)b * COUT * HW + (size_t)h * W_ + px0;
#pragma unroll
    for (int g = 0; g < 4; ++g) {
#pragma unroll
        for (int nf = 0; nf < 4; ++nf)
#pragma unroll
            for (int r = 0; r < 4; ++r)
                myscr[(lhi * 4 + r) * SCW + nf * 16 + llo] = acc[g][nf][r];
        WAIT_LGKM0();                    // scratch writes visible (LDS only)
#pragma unroll
        for (int j = 0; j < 4; ++j) {
            int ocp = j * 4 + lhi;       // 0..15
            f32x4 vv = *(const f32x4*)(myscr + ocp * SCW + llo * 4);
            int oc = g * 16 + ocp;
            *(f32x4*)(obase + (size_t)oc * HW + llo * 4) = vv;
        }
        WAIT_LGKM0();                    // LDS reads done before scratch overwrite
    }
}

// ---------------------------------------------------------------------------
// Fallback: naive fp32 direct conv (only if workspace is too small for Wp)
// ---------------------------------------------------------------------------
__global__ void conv_naive_kernel(const float* __restrict__ in,
                                  const float* __restrict__ wt,
                                  float* __restrict__ out) {
    int idx = blockIdx.x * blockDim.x + threadIdx.x;
    if (idx >= B_ * COUT * HW) return;
    int w  = idx & 127;
    int h  = (idx >> 7) & 127;
    int oc = (idx >> 14) & 63;
    int b  = idx >> 20;
    float s = 0.f;
    for (int c = 0; c < CIN; ++c)
        for (int ky = 0; ky < 3; ++ky) {
            int y = h + ky - 1;
            if ((unsigned)y >= (unsigned)H_) continue;
            for (int kx = 0; kx < 3; ++kx) {
                int x = w + kx - 1;
                if ((unsigned)x >= (unsigned)W_) continue;
                s += in[((size_t)(b * CIN + c) * H_ + y) * W_ + x] *
                     wt[(((size_t)oc * CIN + c) * 3 + ky) * 3 + kx];
            }
        }
    out[idx] = s;
}

extern "C" void kernel_launch(void* const* d_in, const int* in_sizes, int n_in,
                              void* d_out, int out_size, void* d_ws, size_t ws_size,
                              hipStream_t stream) {
    const float* in = (const float*)d_in[0];
    const float* wt = (const float*)d_in[1];
    float* out = (float*)d_out;

    size_t Wp_bytes = (size_t)COUT * CIN * 9 * 2;   // 36,864

    if (ws_size >= Wp_bytes) {
        ushort* Wp = (ushort*)d_ws;
        prep_w_kernel<<<(COUT * CIN * 9 + 255) / 256, 256, 0, stream>>>(wt, Wp);
        conv_fused_kernel<<<B_ * (H_ / T_), NT_, 0, stream>>>(in, Wp, out);
    } else {
        int total = B_ * COUT * HW;
        conv_naive_kernel<<<(total + 255) / 256, 256, 0, stream>>>(in, wt, out);
    }
}

// Round 9
// 52.685 us; speedup vs baseline: 4.8707x; 4.8707x over previous
//
#include <hip/hip_runtime.h>
#include <hip/hip_bf16.h>
#include <stdint.h>

typedef short bf16x8 __attribute__((ext_vector_type(8)));
typedef float f32x4  __attribute__((ext_vector_type(4)));

#define B_   32
#define CIN  32
#define COUT 64
#define H_   128
#define W_   128
#define HW   (H_ * W_)
#define T_   2            // output rows per block
#define RROWS 4           // staged input rows = T_+2
#define PXW  130          // padded width
#define SCW  68           // scratch row stride in words (16B-aligned, bank-spread)

// s_waitcnt imm: vmcnt=63, expcnt=7, lgkmcnt=0  -> wait LDS only, NOT stores
#define WAIT_LGKM0() __builtin_amdgcn_s_waitcnt(0xC07F)

static __device__ __forceinline__ ushort f2bf(float v) {
    __hip_bfloat16 h = __float2bfloat16(v);
    return __builtin_bit_cast(ushort, h);
}

// ---------------------------------------------------------------------------
// Weight pack: [Cout][Cin][3][3] fp32 -> bf16 A-fragment order
// Wp[tap][ocg][lane][j] = W[ocg*16 + (lane&15)][8*(lane>>4)+j][ky][kx]
// ---------------------------------------------------------------------------
__global__ void prep_w_kernel(const float* __restrict__ wt, ushort* __restrict__ Wp) {
    int p = blockIdx.x * blockDim.x + threadIdx.x;
    if (p >= COUT * CIN * 9) return;  // 18432
    int j    = p & 7;
    int lane = (p >> 3) & 63;
    int g    = (p >> 9) & 3;
    int tap  = p >> 11;
    int oc   = g * 16 + (lane & 15);
    int cin  = (lane >> 4) * 8 + j;
    int ky   = tap / 3;
    int kx   = tap % 3;
    Wp[p] = f2bf(wt[(((size_t)oc * CIN + cin) * 3 + ky) * 3 + kx]);
}

// ---------------------------------------------------------------------------
// Fused conv (R6 structure, slim scratch). Stage 4 padded rows (NCHW fp32 ->
// bf16 NHWC in LDS, XOR-swizzled); implicit-GEMM; full-line epilogue batched
// over r: 4-row-per-wave scratch (transpose stays within lhi-group), so LDS
// = 33.3K + 4.3K = 37.6K -> 4 blocks/CU = 16 waves (VGPR cap), ONE barrier,
// per-wave staggered stores. Reg budget: 56 VGPR + 64 acc = 120 <= 512/4.
// ---------------------------------------------------------------------------
__global__ __launch_bounds__(256, 4) void conv_fused_kernel(
    const float* __restrict__ in, const ushort* __restrict__ Wp,
    float* __restrict__ out) {
    __shared__ ushort lds[RROWS * PXW * 32];     // 33,280 B staging
    __shared__ float  scr[4][4 * SCW];           // 4,352 B per-wave scratch

    int hw_blk  = blockIdx.x;
    int logical = (hw_blk & 7) * 256 + (hw_blk >> 3);   // grid = 2048 = 8*256
    int b   = logical >> 6;          // /64
    int h0  = (logical & 63) * T_;
    int tid = threadIdx.x;

    // ---- stage: thread = one (row, px) column, loop 32 channels ----
    for (int i = tid; i < RROWS * PXW; i += 256) {
        int r  = i / PXW;
        int px = i - r * PXW;
        int gy = h0 + r - 1;
        bf16x8 v[4];
        if (gy >= 0 && gy < H_ && px >= 1 && px <= W_) {
            const float* src = in + ((size_t)b * CIN * H_ + gy) * W_ + (px - 1);
#pragma unroll
            for (int q = 0; q < 4; ++q)
#pragma unroll
                for (int j = 0; j < 8; ++j)
                    v[q][j] = (short)f2bf(src[(size_t)(q * 8 + j) * HW]);
        } else {
#pragma unroll
            for (int q = 0; q < 4; ++q)
#pragma unroll
                for (int j = 0; j < 8; ++j)
                    v[q][j] = 0;
        }
        uint32_t base_byte = (uint32_t)i * 64;
        uint32_t sw = ((uint32_t)(px >> 1) & 3u) << 4;
#pragma unroll
        for (int q = 0; q < 4; ++q)
            *(bf16x8*)((char*)lds + base_byte + (((uint32_t)q << 4) ^ sw)) = v[q];
    }
    __syncthreads();

    // ---- compute: wave = (row = wid>>1, px half = wid&1), 64 oc x 64 px ----
    int wid  = tid >> 6;
    int lane = tid & 63;
    int llo  = lane & 15;
    int lhi  = lane >> 4;
    int row  = wid >> 1;            // 0..1
    int px0  = (wid & 1) * 64;
    int h    = h0 + row;

    f32x4 acc[4][4];
#pragma unroll
    for (int g = 0; g < 4; ++g)
#pragma unroll
        for (int nf = 0; nf < 4; ++nf) {
            acc[g][nf][0] = 0.f; acc[g][nf][1] = 0.f;
            acc[g][nf][2] = 0.f; acc[g][nf][3] = 0.f;
        }

#pragma unroll
    for (int tap = 0; tap < 9; ++tap) {
        int dy = tap / 3;
        int dx = tap % 3;
        int rbase = (row + dy) * PXW;
        bf16x8 Af[4];
#pragma unroll
        for (int g = 0; g < 4; ++g)
            Af[g] = *(const bf16x8*)(Wp + ((size_t)(tap * 4 + g) * 64 + lane) * 8);
#pragma unroll
        for (int nf = 0; nf < 4; ++nf) {
            int px = px0 + nf * 16 + llo + dx;
            uint32_t byte = (uint32_t)(rbase + px) * 64u +
                            (((uint32_t)lhi << 4) ^ ((((uint32_t)px >> 1) & 3u) << 4));
            bf16x8 Bf = *(const bf16x8*)((const char*)lds + byte);
#pragma unroll
            for (int g = 0; g < 4; ++g)
                acc[g][nf] = __builtin_amdgcn_mfma_f32_16x16x32_bf16(Af[g], Bf, acc[g][nf], 0, 0, 0);
        }
    }

    // ---- epilogue: batched per-wave LDS transpose -> full-line stores ----
    // acc[g][nf][r] is (oc' = lhi*4+r, px' = nf*16+llo): transpose permutes
    // px within an lhi-group only. Batch r: scratch row = lhi (4 rows/wave),
    // readback f32x4 at px' = llo*4; 16 llo-lanes = 256B contiguous per oc.
    float* myscr = &scr[wid][0];
    float* obase = out + (size_t)b * COUT * HW + (size_t)h * W_ + px0;
#pragma unroll
    for (int g = 0; g < 4; ++g)
#pragma unroll
        for (int br = 0; br < 4; ++br) {
#pragma unroll
            for (int nf = 0; nf < 4; ++nf)
                myscr[lhi * SCW + nf * 16 + llo] = acc[g][nf][br];
            WAIT_LGKM0();                    // scratch writes visible (LDS only)
            f32x4 vv = *(const f32x4*)(myscr + lhi * SCW + llo * 4);
            int oc = g * 16 + lhi * 4 + br;
            *(f32x4*)(obase + (size_t)oc * HW + llo * 4) = vv;
            WAIT_LGKM0();                    // reads done before scratch overwrite
        }
}

// ---------------------------------------------------------------------------
// Fallback: naive fp32 direct conv (only if workspace is too small for Wp)
// ---------------------------------------------------------------------------
__global__ void conv_naive_kernel(const float* __restrict__ in,
                                  const float* __restrict__ wt,
                                  float* __restrict__ out) {
    int idx = blockIdx.x * blockDim.x + threadIdx.x;
    if (idx >= B_ * COUT * HW) return;
    int w  = idx & 127;
    int h  = (idx >> 7) & 127;
    int oc = (idx >> 14) & 63;
    int b  = idx >> 20;
    float s = 0.f;
    for (int c = 0; c < CIN; ++c)
        for (int ky = 0; ky < 3; ++ky) {
            int y = h + ky - 1;
            if ((unsigned)y >= (unsigned)H_) continue;
            for (int kx = 0; kx < 3; ++kx) {
                int x = w + kx - 1;
                if ((unsigned)x >= (unsigned)W_) continue;
                s += in[((size_t)(b * CIN + c) * H_ + y) * W_ + x] *
                     wt[(((size_t)oc * CIN + c) * 3 + ky) * 3 + kx];
            }
        }
    out[idx] = s;
}

extern "C" void kernel_launch(void* const* d_in, const int* in_sizes, int n_in,
                              void* d_out, int out_size, void* d_ws, size_t ws_size,
                              hipStream_t stream) {
    const float* in = (const float*)d_in[0];
    const float* wt = (const float*)d_in[1];
    float* out = (float*)d_out;

    size_t Wp_bytes = (size_t)COUT * CIN * 9 * 2;   // 36,864

    if (ws_size >= Wp_bytes) {
        ushort* Wp = (ushort*)d_ws;
        prep_w_kernel<<<(COUT * CIN * 9 + 255) / 256, 256, 0, stream>>>(wt, Wp);
        conv_fused_kernel<<<B_ * (H_ / T_), 256, 0, stream>>>(in, Wp, out);
    } else {
        int total = B_ * COUT * HW;
        conv_naive_kernel<<<(total + 255) / 256, 256, 0, stream>>>(in, wt, out);
    }
}

// Round 10
// 51.837 us; speedup vs baseline: 4.9504x; 1.0164x over previous
//
#include <hip/hip_runtime.h>
#include <hip/hip_bf16.h>
#include <stdint.h>

typedef short bf16x8 __attribute__((ext_vector_type(8)));
typedef float f32x4  __attribute__((ext_vector_type(4)));

#define B_   32
#define CIN  32
#define COUT 64
#define H_   128
#define W_   128
#define HW   (H_ * W_)
#define WCOLS 66           // 64 px + 2 halo cols per wave tile
#define WROWS 3            // input rows per wave tile
#define WLDS  (WROWS * WCOLS * 32)   // ushorts per wave slice (12,672 B)
#define SCW  68            // scratch row stride in words

// s_waitcnt imm: vmcnt=63, expcnt=7, lgkmcnt=0  -> wait LDS only, NOT stores
#define WAIT_LGKM0() __builtin_amdgcn_s_waitcnt(0xC07F)

static __device__ __forceinline__ ushort f2bf(float v) {
    __hip_bfloat16 h = __float2bfloat16(v);
    return __builtin_bit_cast(ushort, h);
}

// ---------------------------------------------------------------------------
// Weight pack: [Cout][Cin][3][3] fp32 -> bf16 A-fragment order
// Wp[tap][ocg][lane][j] = W[ocg*16 + (lane&15)][8*(lane>>4)+j][ky][kx]
// ---------------------------------------------------------------------------
__global__ void prep_w_kernel(const float* __restrict__ wt, ushort* __restrict__ Wp) {
    int p = blockIdx.x * blockDim.x + threadIdx.x;
    if (p >= COUT * CIN * 9) return;  // 18432
    int j    = p & 7;
    int lane = (p >> 3) & 63;
    int g    = (p >> 9) & 3;
    int tap  = p >> 11;
    int oc   = g * 16 + (lane & 15);
    int cin  = (lane >> 4) * 8 + j;
    int ky   = tap / 3;
    int kx   = tap % 3;
    Wp[p] = f2bf(wt[(((size_t)oc * CIN + cin) * 3 + ky) * 3 + kx]);
}

// ---------------------------------------------------------------------------
// Barrier-free wave-autonomous conv. Each wave owns one 64oc x 64px tile:
// stages its 3x66-col input patch (NCHW fp32 -> bf16 NHWC, XOR-swizzled)
// into a PRIVATE 12.7KB LDS slice, lgkm-waits (no __syncthreads anywhere),
// runs 144 MFMAs, then R6's batched full-line epilogue through the (dead)
// own slice. 4 waves/block x 50.7KB -> 3 blocks/CU = 12 free-running waves.
// ---------------------------------------------------------------------------
__global__ __launch_bounds__(256, 4) void conv_wave_kernel(
    const float* __restrict__ in, const ushort* __restrict__ Wp,
    float* __restrict__ out) {
    __shared__ ushort lds[4 * WLDS];   // 50,688 B

    int hw_blk  = blockIdx.x;
    int logical = (hw_blk & 7) * 256 + (hw_blk >> 3);   // grid = 2048 = 8*256
    int tid  = threadIdx.x;
    int wid  = tid >> 6;
    int lane = tid & 63;
    int llo  = lane & 15;
    int lhi  = lane >> 4;

    int b   = logical >> 6;                  // /64 blocks per image
    int t   = (logical & 63) * 4 + wid;      // wave tile id within image
    int h   = t >> 1;                        // output row
    int px0 = (t & 1) * 64;                  // px half

    ushort* wlds = lds + wid * WLDS;
    const float* ib = in + (size_t)b * CIN * HW;

    // ---- stage: 3 rows x 66 cols, private; lanes = consecutive cols ----
#pragma unroll
    for (int r = 0; r < 3; ++r) {
        int lc  = lane;              // 0..63
        int gy  = h + r - 1;
        int pxg = px0 + lc - 1;
        bf16x8 v[4];
        if (gy >= 0 && gy < H_ && pxg >= 0 && pxg < W_) {
            const float* src = ib + (size_t)gy * W_ + pxg;
#pragma unroll
            for (int q = 0; q < 4; ++q)
#pragma unroll
                for (int j = 0; j < 8; ++j)
                    v[q][j] = (short)f2bf(src[(size_t)(q * 8 + j) * HW]);
        } else {
#pragma unroll
            for (int q = 0; q < 4; ++q)
#pragma unroll
                for (int j = 0; j < 8; ++j)
                    v[q][j] = 0;
        }
        uint32_t base = (uint32_t)(r * WCOLS + lc) * 64u;
        uint32_t sw = (((uint32_t)lc >> 1) & 3u) << 4;
#pragma unroll
        for (int q = 0; q < 4; ++q)
            *(bf16x8*)((char*)wlds + base + (((uint32_t)q << 4) ^ sw)) = v[q];
    }
    // tail: cols 64,65 of each row (6 columns, lanes 0..5)
    if (lane < 6) {
        int r   = lane >> 1;
        int lc  = 64 + (lane & 1);
        int gy  = h + r - 1;
        int pxg = px0 + lc - 1;
        bf16x8 v[4];
        if (gy >= 0 && gy < H_ && pxg >= 0 && pxg < W_) {
            const float* src = ib + (size_t)gy * W_ + pxg;
#pragma unroll
            for (int q = 0; q < 4; ++q)
#pragma unroll
                for (int j = 0; j < 8; ++j)
                    v[q][j] = (short)f2bf(src[(size_t)(q * 8 + j) * HW]);
        } else {
#pragma unroll
            for (int q = 0; q < 4; ++q)
#pragma unroll
                for (int j = 0; j < 8; ++j)
                    v[q][j] = 0;
        }
        uint32_t base = (uint32_t)(r * WCOLS + lc) * 64u;
        uint32_t sw = (((uint32_t)lc >> 1) & 3u) << 4;
#pragma unroll
        for (int q = 0; q < 4; ++q)
            *(bf16x8*)((char*)wlds + base + (((uint32_t)q << 4) ^ sw)) = v[q];
    }
    WAIT_LGKM0();   // own ds_writes visible to own ds_reads (no barrier!)

    // ---- compute: 64 oc x 64 px, 9 taps x 4 nf x 4 g MFMAs ----
    f32x4 acc[4][4];
#pragma unroll
    for (int g = 0; g < 4; ++g)
#pragma unroll
        for (int nf = 0; nf < 4; ++nf) {
            acc[g][nf][0] = 0.f; acc[g][nf][1] = 0.f;
            acc[g][nf][2] = 0.f; acc[g][nf][3] = 0.f;
        }

#pragma unroll
    for (int tap = 0; tap < 9; ++tap) {
        int dy = tap / 3;
        int dx = tap % 3;
        bf16x8 Af[4];
#pragma unroll
        for (int g = 0; g < 4; ++g)
            Af[g] = *(const bf16x8*)(Wp + ((size_t)(tap * 4 + g) * 64 + lane) * 8);
#pragma unroll
        for (int nf = 0; nf < 4; ++nf) {
            int lc = nf * 16 + llo + dx;     // 0..65
            uint32_t byte = (uint32_t)(dy * WCOLS + lc) * 64u +
                            (((uint32_t)lhi << 4) ^ ((((uint32_t)lc >> 1) & 3u) << 4));
            bf16x8 Bf = *(const bf16x8*)((const char*)wlds + byte);
#pragma unroll
            for (int g = 0; g < 4; ++g)
                acc[g][nf] = __builtin_amdgcn_mfma_f32_16x16x32_bf16(Af[g], Bf, acc[g][nf], 0, 0, 0);
        }
    }

    // ---- epilogue: own slice is dead -> per-wave scratch, R6 batching ----
    // acc[g][nf][r] is (oc' = lhi*4+r, px' = nf*16+llo). 16 writes -> wait ->
    // 4 b128 reads -> 4 full-line dwordx4 stores, per g. lgkm-only waits.
    float* myscr = (float*)wlds;
    float* obase = out + (size_t)b * COUT * HW + (size_t)h * W_ + px0;
#pragma unroll
    for (int g = 0; g < 4; ++g) {
#pragma unroll
        for (int nf = 0; nf < 4; ++nf)
#pragma unroll
            for (int r = 0; r < 4; ++r)
                myscr[(lhi * 4 + r) * SCW + nf * 16 + llo] = acc[g][nf][r];
        WAIT_LGKM0();
#pragma unroll
        for (int j = 0; j < 4; ++j) {
            int ocp = j * 4 + lhi;           // 0..15
            f32x4 vv = *(const f32x4*)(myscr + ocp * SCW + llo * 4);
            int oc = g * 16 + ocp;
            *(f32x4*)(obase + (size_t)oc * HW + llo * 4) = vv;
        }
        WAIT_LGKM0();
    }
}

// ---------------------------------------------------------------------------
// Fallback: naive fp32 direct conv (only if workspace is too small for Wp)
// ---------------------------------------------------------------------------
__global__ void conv_naive_kernel(const float* __restrict__ in,
                                  const float* __restrict__ wt,
                                  float* __restrict__ out) {
    int idx = blockIdx.x * blockDim.x + threadIdx.x;
    if (idx >= B_ * COUT * HW) return;
    int w  = idx & 127;
    int h  = (idx >> 7) & 127;
    int oc = (idx >> 14) & 63;
    int b  = idx >> 20;
    float s = 0.f;
    for (int c = 0; c < CIN; ++c)
        for (int ky = 0; ky < 3; ++ky) {
            int y = h + ky - 1;
            if ((unsigned)y >= (unsigned)H_) continue;
            for (int kx = 0; kx < 3; ++kx) {
                int x = w + kx - 1;
                if ((unsigned)x >= (unsigned)W_) continue;
                s += in[((size_t)(b * CIN + c) * H_ + y) * W_ + x] *
                     wt[(((size_t)oc * CIN + c) * 3 + ky) * 3 + kx];
            }
        }
    out[idx] = s;
}

extern "C" void kernel_launch(void* const* d_in, const int* in_sizes, int n_in,
                              void* d_out, int out_size, void* d_ws, size_t ws_size,
                              hipStream_t stream) {
    const float* in = (const float*)d_in[0];
    const float* wt = (const float*)d_in[1];
    float* out = (float*)d_out;

    size_t Wp_bytes = (size_t)COUT * CIN * 9 * 2;   // 36,864

    if (ws_size >= Wp_bytes) {
        ushort* Wp = (ushort*)d_ws;
        prep_w_kernel<<<(COUT * CIN * 9 + 255) / 256, 256, 0, stream>>>(wt, Wp);
        conv_wave_kernel<<<2048, 256, 0, stream>>>(in, Wp, out);
    } else {
        int total = B_ * COUT * HW;
        conv_naive_kernel<<<(total + 255) / 256, 256, 0, stream>>>(in, wt, out);
    }
}

// Round 11
// 46.553 us; speedup vs baseline: 5.5123x; 1.1135x over previous
//
#include <hip/hip_runtime.h>
#include <hip/hip_bf16.h>
#include <stdint.h>

typedef short bf16x8 __attribute__((ext_vector_type(8)));
typedef float f32x4  __attribute__((ext_vector_type(4)));

#define B_   32
#define CIN  32
#define COUT 64
#define H_   128
#define W_   128
#define HW   (H_ * W_)
#define T_   2            // output rows per block
#define RROWS 4           // staged input rows = T_+2
#define PXW  130          // padded width
#define SCW  68           // scratch row stride in words (16B-aligned, 2-way banks)

// s_waitcnt imm: vmcnt=63, expcnt=7, lgkmcnt=0  -> wait LDS only, NOT stores
#define WAIT_LGKM0() __builtin_amdgcn_s_waitcnt(0xC07F)

static __device__ __forceinline__ ushort f2bf(float v) {
    __hip_bfloat16 h = __float2bfloat16(v);
    return __builtin_bit_cast(ushort, h);
}

// ---------------------------------------------------------------------------
// Weight pack: [Cout][Cin][3][3] fp32 -> bf16 A-fragment order
// Wp[tap][ocg][lane][j] = W[ocg*16 + (lane&15)][8*(lane>>4)+j][ky][kx]
// ---------------------------------------------------------------------------
__global__ void prep_w_kernel(const float* __restrict__ wt, ushort* __restrict__ Wp) {
    int p = blockIdx.x * blockDim.x + threadIdx.x;
    if (p >= COUT * CIN * 9) return;  // 18432
    int j    = p & 7;
    int lane = (p >> 3) & 63;
    int g    = (p >> 9) & 3;
    int tap  = p >> 11;
    int oc   = g * 16 + (lane & 15);
    int cin  = (lane >> 4) * 8 + j;
    int ky   = tap / 3;
    int kx   = tap % 3;
    Wp[p] = f2bf(wt[(((size_t)oc * CIN + cin) * 3 + ky) * 3 + kx]);
}

// ---------------------------------------------------------------------------
// R6 structure (best: 48.6us) + NONTEMPORAL full-line epilogue stores.
// Rationale: R4 counters show mixed HBM read+write streams run at ~2.8-4
// TB/s (turnaround), pure-write fills at 7 TB/s. Output allocating into L3
// evicts the (otherwise resident) input each replay (FETCH~33MB). nt stores
// on 256B-contiguous, 256B-aligned dwordx4 bursts bypass L3 without write
// amplification (R4's amplification came from 64B segments; these are full
// lines) -> input stays L3-hot, HBM stream becomes write-pure.
// ---------------------------------------------------------------------------
__global__ __launch_bounds__(256, 3) void conv_fused_kernel(
    const float* __restrict__ in, const ushort* __restrict__ Wp,
    float* __restrict__ out) {
    __shared__ ushort lds[RROWS * PXW * 32];     // 33,280 B
    __shared__ float  scr[4][16 * SCW];          // 17,408 B (per-wave scratch)

    int hw_blk  = blockIdx.x;
    int logical = (hw_blk & 7) * 256 + (hw_blk >> 3);   // grid = 2048 = 8*256
    int b   = logical >> 6;          // /64
    int h0  = (logical & 63) * T_;
    int tid = threadIdx.x;

    // ---- stage: thread = one (row, px) column, loop 32 channels ----
    for (int i = tid; i < RROWS * PXW; i += 256) {
        int r  = i / PXW;
        int px = i - r * PXW;
        int gy = h0 + r - 1;
        bf16x8 v[4];
        if (gy >= 0 && gy < H_ && px >= 1 && px <= W_) {
            const float* src = in + ((size_t)b * CIN * H_ + gy) * W_ + (px - 1);
#pragma unroll
            for (int q = 0; q < 4; ++q)
#pragma unroll
                for (int j = 0; j < 8; ++j)
                    v[q][j] = (short)f2bf(src[(size_t)(q * 8 + j) * HW]);
        } else {
#pragma unroll
            for (int q = 0; q < 4; ++q)
#pragma unroll
                for (int j = 0; j < 8; ++j)
                    v[q][j] = 0;
        }
        uint32_t base_byte = (uint32_t)i * 64;
        uint32_t sw = ((uint32_t)(px >> 1) & 3u) << 4;
#pragma unroll
        for (int q = 0; q < 4; ++q)
            *(bf16x8*)((char*)lds + base_byte + (((uint32_t)q << 4) ^ sw)) = v[q];
    }
    __syncthreads();

    // ---- compute: wave = (row = wid>>1, px half = wid&1), 64 oc x 64 px ----
    int wid  = tid >> 6;
    int lane = tid & 63;
    int llo  = lane & 15;
    int lhi  = lane >> 4;
    int row  = wid >> 1;            // 0..1
    int px0  = (wid & 1) * 64;
    int h    = h0 + row;

    f32x4 acc[4][4];
#pragma unroll
    for (int g = 0; g < 4; ++g)
#pragma unroll
        for (int nf = 0; nf < 4; ++nf) {
            acc[g][nf][0] = 0.f; acc[g][nf][1] = 0.f;
            acc[g][nf][2] = 0.f; acc[g][nf][3] = 0.f;
        }

#pragma unroll
    for (int tap = 0; tap < 9; ++tap) {
        int dy = tap / 3;
        int dx = tap % 3;
        int rbase = (row + dy) * PXW;
        bf16x8 Af[4];
#pragma unroll
        for (int g = 0; g < 4; ++g)
            Af[g] = *(const bf16x8*)(Wp + ((size_t)(tap * 4 + g) * 64 + lane) * 8);
#pragma unroll
        for (int nf = 0; nf < 4; ++nf) {
            int px = px0 + nf * 16 + llo + dx;
            uint32_t byte = (uint32_t)(rbase + px) * 64u +
                            (((uint32_t)lhi << 4) ^ ((((uint32_t)px >> 1) & 3u) << 4));
            bf16x8 Bf = *(const bf16x8*)((const char*)lds + byte);
#pragma unroll
            for (int g = 0; g < 4; ++g)
                acc[g][nf] = __builtin_amdgcn_mfma_f32_16x16x32_bf16(Af[g], Bf, acc[g][nf], 0, 0, 0);
        }
    }

    // ---- epilogue: per-wave LDS transpose -> full-line NT dwordx4 stores --
    // acc[g][nf][r] is (oc' = lhi*4+r, px' = nf*16+llo). Readback: oc'=j*4+lhi,
    // px' = llo*4..+3 -> f32x4; 16 llo-lanes = 256B contiguous, 256B-aligned
    // (2 full cache lines) per oc row -> nontemporal is safe (no RFO, no
    // fragmentation) and keeps the output stream out of L2/L3.
    float* myscr = &scr[wid][0];
    float* obase = out + (size_t)b * COUT * HW + (size_t)h * W_ + px0;
#pragma unroll
    for (int g = 0; g < 4; ++g) {
#pragma unroll
        for (int nf = 0; nf < 4; ++nf)
#pragma unroll
            for (int r = 0; r < 4; ++r)
                myscr[(lhi * 4 + r) * SCW + nf * 16 + llo] = acc[g][nf][r];
        WAIT_LGKM0();                    // scratch writes visible (LDS only)
#pragma unroll
        for (int j = 0; j < 4; ++j) {
            int ocp = j * 4 + lhi;       // 0..15
            f32x4 vv = *(const f32x4*)(myscr + ocp * SCW + llo * 4);
            int oc = g * 16 + ocp;
            float* dst = obase + (size_t)oc * HW + llo * 4;
#pragma unroll
            for (int k = 0; k < 4; ++k)
                __builtin_nontemporal_store(vv[k], dst + k);
        }
        WAIT_LGKM0();                    // LDS reads done before scratch overwrite
    }
}

// ---------------------------------------------------------------------------
// Fallback: naive fp32 direct conv (only if workspace is too small for Wp)
// ---------------------------------------------------------------------------
__global__ void conv_naive_kernel(const float* __restrict__ in,
                                  const float* __restrict__ wt,
                                  float* __restrict__ out) {
    int idx = blockIdx.x * blockDim.x + threadIdx.x;
    if (idx >= B_ * COUT * HW) return;
    int w  = idx & 127;
    int h  = (idx >> 7) & 127;
    int oc = (idx >> 14) & 63;
    int b  = idx >> 20;
    float s = 0.f;
    for (int c = 0; c < CIN; ++c)
        for (int ky = 0; ky < 3; ++ky) {
            int y = h + ky - 1;
            if ((unsigned)y >= (unsigned)H_) continue;
            for (int kx = 0; kx < 3; ++kx) {
                int x = w + kx - 1;
                if ((unsigned)x >= (unsigned)W_) continue;
                s += in[((size_t)(b * CIN + c) * H_ + y) * W_ + x] *
                     wt[(((size_t)oc * CIN + c) * 3 + ky) * 3 + kx];
            }
        }
    out[idx] = s;
}

extern "C" void kernel_launch(void* const* d_in, const int* in_sizes, int n_in,
                              void* d_out, int out_size, void* d_ws, size_t ws_size,
                              hipStream_t stream) {
    const float* in = (const float*)d_in[0];
    const float* wt = (const float*)d_in[1];
    float* out = (float*)d_out;

    size_t Wp_bytes = (size_t)COUT * CIN * 9 * 2;   // 36,864

    if (ws_size >= Wp_bytes) {
        ushort* Wp = (ushort*)d_ws;
        prep_w_kernel<<<(COUT * CIN * 9 + 255) / 256, 256, 0, stream>>>(wt, Wp);
        conv_fused_kernel<<<B_ * (H_ / T_), 256, 0, stream>>>(in, Wp, out);
    } else {
        int total = B_ * COUT * HW;
        conv_naive_kernel<<<(total + 255) / 256, 256, 0, stream>>>(in, wt, out);
    }
}

// Round 12
// 46.307 us; speedup vs baseline: 5.5416x; 1.0053x over previous
//
#include <hip/hip_runtime.h>
#include <hip/hip_bf16.h>
#include <stdint.h>

typedef short bf16x8 __attribute__((ext_vector_type(8)));
typedef float f32x4  __attribute__((ext_vector_type(4)));

#define B_   32
#define CIN  32
#define COUT 64
#define H_   128
#define W_   128
#define HW   (H_ * W_)
#define T_   2            // output rows per block
#define RROWS 4           // staged input rows = T_+2
#define PXW  130          // padded width
#define SCW  68           // scratch row stride in words (16B-aligned, 2-way banks)

// s_waitcnt imm: vmcnt=63, expcnt=7, lgkmcnt=0  -> wait LDS only, NOT stores
#define WAIT_LGKM0() __builtin_amdgcn_s_waitcnt(0xC07F)

static __device__ __forceinline__ ushort f2bf(float v) {
    __hip_bfloat16 h = __float2bfloat16(v);
    return __builtin_bit_cast(ushort, h);
}

// ---------------------------------------------------------------------------
// Weight pack: [Cout][Cin][3][3] fp32 -> bf16 A-fragment order
// Wp[tap][ocg][lane][j] = W[ocg*16 + (lane&15)][8*(lane>>4)+j][ky][kx]
// ---------------------------------------------------------------------------
__global__ void prep_w_kernel(const float* __restrict__ wt, ushort* __restrict__ Wp) {
    int p = blockIdx.x * blockDim.x + threadIdx.x;
    if (p >= COUT * CIN * 9) return;  // 18432
    int j    = p & 7;
    int lane = (p >> 3) & 63;
    int g    = (p >> 9) & 3;
    int tap  = p >> 11;
    int oc   = g * 16 + (lane & 15);
    int cin  = (lane >> 4) * 8 + j;
    int ky   = tap / 3;
    int kx   = tap % 3;
    Wp[p] = f2bf(wt[(((size_t)oc * CIN + cin) * 3 + ky) * 3 + kx]);
}

// ---------------------------------------------------------------------------
// R11 structure (best: 46.55us) + store-burst smoothing: compute in TWO
// oc-half passes (2 g's each, taps replayed), storing each half immediately
// -> 2 evenly spaced store bursts per wave; (wid&1) rotation decorrelates
// which half neighboring waves store first. Epilogue unchanged: per-wave LDS
// transpose -> 256B-contiguous nontemporal dwordx4 (full lines, no RFO,
// no L3 pollution). Cost: Bf LDS reads x2 (~6us aggregate, hidden).
// ---------------------------------------------------------------------------
__global__ __launch_bounds__(256, 3) void conv_fused_kernel(
    const float* __restrict__ in, const ushort* __restrict__ Wp,
    float* __restrict__ out) {
    __shared__ ushort lds[RROWS * PXW * 32];     // 33,280 B
    __shared__ float  scr[4][16 * SCW];          // 17,408 B (per-wave scratch)

    int hw_blk  = blockIdx.x;
    int logical = (hw_blk & 7) * 256 + (hw_blk >> 3);   // grid = 2048 = 8*256
    int b   = logical >> 6;          // /64
    int h0  = (logical & 63) * T_;
    int tid = threadIdx.x;

    // ---- stage: thread = one (row, px) column, loop 32 channels ----
    for (int i = tid; i < RROWS * PXW; i += 256) {
        int r  = i / PXW;
        int px = i - r * PXW;
        int gy = h0 + r - 1;
        bf16x8 v[4];
        if (gy >= 0 && gy < H_ && px >= 1 && px <= W_) {
            const float* src = in + ((size_t)b * CIN * H_ + gy) * W_ + (px - 1);
#pragma unroll
            for (int q = 0; q < 4; ++q)
#pragma unroll
                for (int j = 0; j < 8; ++j)
                    v[q][j] = (short)f2bf(src[(size_t)(q * 8 + j) * HW]);
        } else {
#pragma unroll
            for (int q = 0; q < 4; ++q)
#pragma unroll
                for (int j = 0; j < 8; ++j)
                    v[q][j] = 0;
        }
        uint32_t base_byte = (uint32_t)i * 64;
        uint32_t sw = ((uint32_t)(px >> 1) & 3u) << 4;
#pragma unroll
        for (int q = 0; q < 4; ++q)
            *(bf16x8*)((char*)lds + base_byte + (((uint32_t)q << 4) ^ sw)) = v[q];
    }
    __syncthreads();

    // ---- compute: wave = (row = wid>>1, px half = wid&1), 64 oc x 64 px ----
    int wid  = tid >> 6;
    int lane = tid & 63;
    int llo  = lane & 15;
    int lhi  = lane >> 4;
    int row  = wid >> 1;            // 0..1
    int px0  = (wid & 1) * 64;
    int h    = h0 + row;

    float* myscr = &scr[wid][0];
    float* obase = out + (size_t)b * COUT * HW + (size_t)h * W_ + px0;

#pragma unroll
    for (int p = 0; p < 2; ++p) {
        int gp = ((p + (wid & 1)) & 1) * 2;    // oc-half for this pass: g in {gp, gp+1}

        f32x4 acc[2][4];
#pragma unroll
        for (int gi = 0; gi < 2; ++gi)
#pragma unroll
            for (int nf = 0; nf < 4; ++nf) {
                acc[gi][nf][0] = 0.f; acc[gi][nf][1] = 0.f;
                acc[gi][nf][2] = 0.f; acc[gi][nf][3] = 0.f;
            }

#pragma unroll
        for (int tap = 0; tap < 9; ++tap) {
            int dy = tap / 3;
            int dx = tap % 3;
            int rbase = (row + dy) * PXW;
            bf16x8 Af[2];
#pragma unroll
            for (int gi = 0; gi < 2; ++gi)
                Af[gi] = *(const bf16x8*)(Wp + ((size_t)(tap * 4 + gp + gi) * 64 + lane) * 8);
#pragma unroll
            for (int nf = 0; nf < 4; ++nf) {
                int px = px0 + nf * 16 + llo + dx;
                uint32_t byte = (uint32_t)(rbase + px) * 64u +
                                (((uint32_t)lhi << 4) ^ ((((uint32_t)px >> 1) & 3u) << 4));
                bf16x8 Bf = *(const bf16x8*)((const char*)lds + byte);
#pragma unroll
                for (int gi = 0; gi < 2; ++gi)
                    acc[gi][nf] = __builtin_amdgcn_mfma_f32_16x16x32_bf16(Af[gi], Bf, acc[gi][nf], 0, 0, 0);
            }
        }

        // ---- store this oc-half now (full-line NT dwordx4 via scratch) ----
#pragma unroll
        for (int gi = 0; gi < 2; ++gi) {
            int g = gp + gi;
#pragma unroll
            for (int nf = 0; nf < 4; ++nf)
#pragma unroll
                for (int r = 0; r < 4; ++r)
                    myscr[(lhi * 4 + r) * SCW + nf * 16 + llo] = acc[gi][nf][r];
            WAIT_LGKM0();                    // scratch writes visible (LDS only)
#pragma unroll
            for (int j = 0; j < 4; ++j) {
                int ocp = j * 4 + lhi;       // 0..15
                f32x4 vv = *(const f32x4*)(myscr + ocp * SCW + llo * 4);
                int oc = g * 16 + ocp;
                float* dst = obase + (size_t)oc * HW + llo * 4;
#pragma unroll
                for (int k = 0; k < 4; ++k)
                    __builtin_nontemporal_store(vv[k], dst + k);
            }
            WAIT_LGKM0();                    // LDS reads done before scratch overwrite
        }
    }
}

// ---------------------------------------------------------------------------
// Fallback: naive fp32 direct conv (only if workspace is too small for Wp)
// ---------------------------------------------------------------------------
__global__ void conv_naive_kernel(const float* __restrict__ in,
                                  const float* __restrict__ wt,
                                  float* __restrict__ out) {
    int idx = blockIdx.x * blockDim.x + threadIdx.x;
    if (idx >= B_ * COUT * HW) return;
    int w  = idx & 127;
    int h  = (idx >> 7) & 127;
    int oc = (idx >> 14) & 63;
    int b  = idx >> 20;
    float s = 0.f;
    for (int c = 0; c < CIN; ++c)
        for (int ky = 0; ky < 3; ++ky) {
            int y = h + ky - 1;
            if ((unsigned)y >= (unsigned)H_) continue;
            for (int kx = 0; kx < 3; ++kx) {
                int x = w + kx - 1;
                if ((unsigned)x >= (unsigned)W_) continue;
                s += in[((size_t)(b * CIN + c) * H_ + y) * W_ + x] *
                     wt[(((size_t)oc * CIN + c) * 3 + ky) * 3 + kx];
            }
        }
    out[idx] = s;
}

extern "C" void kernel_launch(void* const* d_in, const int* in_sizes, int n_in,
                              void* d_out, int out_size, void* d_ws, size_t ws_size,
                              hipStream_t stream) {
    const float* in = (const float*)d_in[0];
    const float* wt = (const float*)d_in[1];
    float* out = (float*)d_out;

    size_t Wp_bytes = (size_t)COUT * CIN * 9 * 2;   // 36,864

    if (ws_size >= Wp_bytes) {
        ushort* Wp = (ushort*)d_ws;
        prep_w_kernel<<<(COUT * CIN * 9 + 255) / 256, 256, 0, stream>>>(wt, Wp);
        conv_fused_kernel<<<B_ * (H_ / T_), 256, 0, stream>>>(in, Wp, out);
    } else {
        int total = B_ * COUT * HW;
        conv_naive_kernel<<<(total + 255) / 256, 256, 0, stream>>>(in, wt, out);
    }
}